// Round 1
// baseline (153.746 us; speedup 1.0000x reference)
//
#include <hip/hip_runtime.h>
#include <cstdint>
#include <cstddef>

// Problem constants: B=2, N=16384, K=32, F=64, E=16
#define LOGN 14

typedef __bf16 bf16x8 __attribute__((ext_vector_type(8)));
typedef float f32x4 __attribute__((ext_vector_type(4)));
typedef unsigned u32;

// raw barrier + lgkmcnt(0)-only wait (vmcnt/expcnt unconstrained: 0xC07F)
#define BARRIER() __builtin_amdgcn_s_barrier()
#define LGKM0()   __builtin_amdgcn_s_waitcnt(0xC07F)

__device__ __forceinline__ u32 fbits(float f) { return __builtin_bit_cast(u32, f); }
// pack two f32 -> dword of 2 bf16 (RNE), lo -> low16
__device__ __forceinline__ u32 pkrne(float lo, float hi) {
  u32 a = fbits(lo); a = a + 0x7fffu + ((a >> 16) & 1u);
  u32 b = fbits(hi); b = b + 0x7fffu + ((b >> 16) & 1u);
  return (b & 0xffff0000u) | (a >> 16);
}

// wt[m][k] = w[l][m][n]/32, k = l*16+n (bf16), 64x1024 = 128KB
__global__ void prep_wt(const float* __restrict__ w, unsigned short* __restrict__ wt) {
  int idx = blockIdx.x * 256 + threadIdx.x;
  int m = idx >> 10, k = idx & 1023, l = k >> 4, n = k & 15;
  u32 u = fbits(w[l * 1024 + m * 16 + n] * 0.03125f);
  wt[idx] = (unsigned short)((u + 0x7fffu + ((u >> 16) & 1u)) >> 16);
}

__device__ __forceinline__ bf16x8 mk_bw(const float* wp) {
  float v[8];
  #pragma unroll
  for (int i = 0; i < 8; ++i) v[i] = wp[i] * 0.03125f;
  uint4 pk{pkrne(v[0], v[1]), pkrne(v[2], v[3]), pkrne(v[4], v[5]), pkrne(v[6], v[7])};
  return __builtin_bit_cast(bf16x8, pk);
}

// ============================================================================
// WG = 256 threads (4 waves) = 16 nodes; wave wid owns nodes wid*4..wid*4+3
// end-to-end in phase A — NO barriers, NO S/E LDS staging (R6's DS-pipe bind).
// Per node: MFMA fragments gathered DIRECTLY from global in frag layout:
//   A-frag lane(q,c) reg i = E[j=q*8+i][n=c]      (coalesced 256B/instr)
//   B-frag lane(q,c) reg i = S[j=q*8+i][L=lt*16+c] (4 l-tiles share one row
//     base -> 4 dword loads w/ imm offsets, one 64b addr calc per row)
//   Row indices: per-lane int4 pair from nlist (quadrant-broadcast loads).
// Depth-2 software pipeline: nl 2 nodes ahead, S/E 1 node ahead; all waits are
// precise vmcnt on plain loads. 4 MFMAs/node -> G (bf16, RNE) -> 4 ds_write_b64
// into g_lds (k-chunk layout, chunk = 2L+(q>>1) ^ node&7). LDS = 32 KB only.
// Phase B (unchanged from R6): wave wid = m-tile; 32 K-steps x
// (ds_read_b128 A + 16B wt load + MFMA); wt is L2-resident.
//
// R7: __launch_bounds__(256,3) -> (256,5). Profile showed MfmaUtil 3.5% /
// VALUBusy 19% / HBM 17% / Occupancy 36.7% (= exactly the 3 blocks/CU the old
// bound requested) — latency-bound on the phase-A gather with every pipe idle.
// VGPR=52 (cap for 5 w/EU is 102) and LDS=32KB (160/32 = 5 blocks) both admit
// 5 blocks/CU = 20 waves/CU; LDS is now the binding resource. Pure TLP gain.
// ============================================================================
template <bool USE_WT>
__global__ __launch_bounds__(256, 5)
void mp_kernel(const float* __restrict__ nodes, const int* __restrict__ nlist,
               const float* __restrict__ edges, const unsigned short* __restrict__ wt,
               const float* __restrict__ w, float* __restrict__ out) {
  __shared__ u32 g_lds[16 * 512];   // 32 KB: G (bf16) in phase-B A-frag order

  const int tid = threadIdx.x;
  const int lane = tid & 63;
  const int wid = __builtin_amdgcn_readfirstlane(tid >> 6);
  const int q = lane >> 4, c = lane & 15;

  // XCD-aware mapping: batch b's 4 MB nodes slab pinned to 4 XCDs' L2.
  const int blk = blockIdx.x;
  const int xcd = blk & 7;
  const int batch = xcd >> 2;
  const int ordinal = ((blk >> 3) << 2) + (xcd & 3);    // [0,1024)
  const int wg0 = (batch << LOGN) + (ordinal << 4);
  const float* __restrict__ nbase = nodes + ((size_t)batch << 20);

  const int nd0 = wid << 2;                              // this wave's first node

  auto issue_nl = [&](int t, int4* ni) {
    const int* r = nlist + (((size_t)(wg0 + nd0 + t)) << 5) + (q << 3);
    ni[0] = *(const int4*)r;        // ix[q*8+0 .. +3]
    ni[1] = *(const int4*)(r + 4);  // ix[q*8+4 .. +7]
  };
  auto issue_se = [&](int t, const int4* ni, float* S, float* E) {
    const int ix[8] = {ni[0].x, ni[0].y, ni[0].z, ni[0].w,
                       ni[1].x, ni[1].y, ni[1].z, ni[1].w};
    #pragma unroll
    for (int i = 0; i < 8; ++i) {
      const float* rp = nbase + ((size_t)(u32)ix[i] << 6) + c;
      #pragma unroll
      for (int lt = 0; lt < 4; ++lt) S[i * 4 + lt] = rp[lt << 4];
    }
    const float* ep = edges + (((size_t)(wg0 + nd0 + t)) << 9) + (q << 7) + c;
    #pragma unroll
    for (int i = 0; i < 8; ++i) E[i] = ep[i << 4];
  };
  auto consume = [&](int p, const float* S, const float* E) {
    uint4 apk{pkrne(E[0], E[1]), pkrne(E[2], E[3]),
              pkrne(E[4], E[5]), pkrne(E[6], E[7])};
    const bf16x8 af = __builtin_bit_cast(bf16x8, apk);
    #pragma unroll
    for (int lt = 0; lt < 4; ++lt) {
      uint4 spk{pkrne(S[0 * 4 + lt], S[1 * 4 + lt]),
                pkrne(S[2 * 4 + lt], S[3 * 4 + lt]),
                pkrne(S[4 * 4 + lt], S[5 * 4 + lt]),
                pkrne(S[6 * 4 + lt], S[7 * 4 + lt])};
      f32x4 acc{0.f, 0.f, 0.f, 0.f};
      acc = __builtin_amdgcn_mfma_f32_16x16x32_bf16(af,
              __builtin_bit_cast(bf16x8, spk), acc, 0, 0, 0);
      // lane holds G^T[n=4q+r][L=lt*16+c]; chunk = (2L+(q>>1)) ^ (p&7)
      const u32 lo = pkrne(acc[0], acc[1]);
      const u32 hi = pkrne(acc[2], acc[3]);
      const int chunk = ((((lt << 4) + c) << 1) + (q >> 1)) ^ (p & 7);
      *(uint2*)&g_lds[(p << 9) + (chunk << 2) + ((q & 1) << 1)] = uint2{lo, hi};
    }
  };

  // ---------------- Phase A: barrier-free depth-2 pipeline ----------------
  {
    int4 ni0[2], ni1[2];
    float S0[32], E0[8], S1[32], E1[8];
    issue_nl(0, ni0);
    issue_nl(1, ni1);
    issue_se(0, ni0, S0, E0);       // waits nl(0) only; nl(1) stays in flight
    issue_nl(2, ni0);
    issue_se(1, ni1, S1, E1);       // waits nl(1); SE(0)+nl(2) in flight
    issue_nl(3, ni1);
    consume(nd0 + 0, S0, E0);       // waits SE(0); SE(1)+nl(3) in flight
    issue_se(2, ni0, S0, E0);
    consume(nd0 + 1, S1, E1);
    issue_se(3, ni1, S1, E1);
    consume(nd0 + 2, S0, E0);
    consume(nd0 + 3, S1, E1);
  }

  LGKM0();      // G writes visible
  BARRIER();

  // ---------------- Phase B: out[node][m] = sum_k G2[node][k] * wt[m][k] ----
  // A-frag: lane(q,c): G2[node=c][k=32s+8q+i] -> chunk 4s+q (^c&7), b128.
  const int m = (wid << 4) + c;
  f32x4 ob{0.f, 0.f, 0.f, 0.f};
  if (USE_WT) {
    const unsigned short* wb = wt + ((size_t)m << 10) + (q << 3);
    #pragma unroll 8
    for (int s = 0; s < 32; ++s) {
      uint4 ar = *(const uint4*)&g_lds[(c << 9) + ((((s << 2) + q) ^ (c & 7)) << 2)];
      ob = __builtin_amdgcn_mfma_f32_16x16x32_bf16(__builtin_bit_cast(bf16x8, ar),
                                                   *(const bf16x8*)(wb + (s << 5)),
                                                   ob, 0, 0, 0);
    }
  } else {
    #pragma unroll 4
    for (int s = 0; s < 32; ++s) {
      uint4 ar = *(const uint4*)&g_lds[(c << 9) + ((((s << 2) + q) ^ (c & 7)) << 2)];
      const int l = 2 * s + (q >> 1);
      const float* wp = w + l * 1024 + m * 16 + ((q & 1) << 3);
      ob = __builtin_amdgcn_mfma_f32_16x16x32_bf16(__builtin_bit_cast(bf16x8, ar),
                                                   mk_bw(wp), ob, 0, 0, 0);
    }
  }

  // D: lane(q,c): out[node = 4q+r][mfeat = m]
  #pragma unroll
  for (int r = 0; r < 4; ++r)
    out[((size_t)(wg0 + (q << 2) + r) << 6) + m] = ob[r];
}

extern "C" void kernel_launch(void* const* d_in, const int* in_sizes, int n_in,
                              void* d_out, int out_size, void* d_ws, size_t ws_size,
                              hipStream_t stream) {
  const float* nodes = (const float*)d_in[0];
  const int*   nlist = (const int*)d_in[1];
  const float* edges = (const float*)d_in[2];
  const float* w     = (const float*)d_in[3];
  float* out = (float*)d_out;

  if (ws_size >= 131072) {
    unsigned short* wt = (unsigned short*)d_ws;
    prep_wt<<<256, 256, 0, stream>>>(w, wt);
    mp_kernel<true><<<2048, 256, 0, stream>>>(nodes, nlist, edges, wt, w, out);
  } else {
    mp_kernel<false><<<2048, 256, 0, stream>>>(nodes, nlist, edges, nullptr, w, out);
  }
}

// Round 2
// 147.571 us; speedup vs baseline: 1.0418x; 1.0418x over previous
//
#include <hip/hip_runtime.h>
#include <cstdint>
#include <cstddef>

// Problem constants: B=2, N=16384, K=32, F=64, E=16
#define LOGN 14

typedef __bf16 bf16x8 __attribute__((ext_vector_type(8)));
typedef float f32x4 __attribute__((ext_vector_type(4)));
typedef unsigned u32;

// raw barrier + lgkmcnt(0)-only wait (vmcnt/expcnt unconstrained: 0xC07F)
#define BARRIER() __builtin_amdgcn_s_barrier()
#define LGKM0()   __builtin_amdgcn_s_waitcnt(0xC07F)
// full scheduling fence: nothing moves across (pins the SW pipeline)
#define SFENCE()  __builtin_amdgcn_sched_barrier(0)

__device__ __forceinline__ u32 fbits(float f) { return __builtin_bit_cast(u32, f); }
// pack two f32 -> dword of 2 bf16 (RNE), lo -> low16
__device__ __forceinline__ u32 pkrne(float lo, float hi) {
  u32 a = fbits(lo); a = a + 0x7fffu + ((a >> 16) & 1u);
  u32 b = fbits(hi); b = b + 0x7fffu + ((b >> 16) & 1u);
  return (b & 0xffff0000u) | (a >> 16);
}

// wt[m][k] = w[l][m][n]/32, k = l*16+n (bf16), 64x1024 = 128KB
__global__ void prep_wt(const float* __restrict__ w, unsigned short* __restrict__ wt) {
  int idx = blockIdx.x * 256 + threadIdx.x;
  int m = idx >> 10, k = idx & 1023, l = k >> 4, n = k & 15;
  u32 u = fbits(w[l * 1024 + m * 16 + n] * 0.03125f);
  wt[idx] = (unsigned short)((u + 0x7fffu + ((u >> 16) & 1u)) >> 16);
}

__device__ __forceinline__ bf16x8 mk_bw(const float* wp) {
  float v[8];
  #pragma unroll
  for (int i = 0; i < 8; ++i) v[i] = wp[i] * 0.03125f;
  uint4 pk{pkrne(v[0], v[1]), pkrne(v[2], v[3]), pkrne(v[4], v[5]), pkrne(v[6], v[7])};
  return __builtin_bit_cast(bf16x8, pk);
}

// ============================================================================
// WG = 256 threads (4 waves) = 16 nodes; wave wid owns nodes wid*4..wid*4+3
// end-to-end in phase A — NO barriers, NO S/E LDS staging (R6's DS-pipe bind).
// Per node: MFMA fragments gathered DIRECTLY from global in frag layout:
//   A-frag lane(q,c) reg i = E[j=q*8+i][n=c]      (coalesced 256B/instr)
//   B-frag lane(q,c) reg i = S[j=q*8+i][L=lt*16+c] (4 l-tiles share one row
//     base -> 4 dword loads w/ imm offsets, one 64b addr calc per row)
//   Row indices: per-lane int4 pair from nlist (quadrant-broadcast loads).
// Depth-2 software pipeline: nl 2 nodes ahead, S/E 1 node ahead; all waits are
// precise vmcnt on plain loads. 4 MFMAs/node -> G (bf16, RNE) -> 4 ds_write_b64
// into g_lds (k-chunk layout, chunk = 2L+(q>>1) ^ node&7). LDS = 32 KB only.
// Phase B: wave wid = m-tile; 32 K-steps x
// (ds_read_b128 A + 16B wt load + MFMA); wt is L2-resident.
//
// R7 (FAILED): launch_bounds (256,3)->(256,5). Occupancy did NOT move (38%);
// FETCH/WRITE each +12 MB = scratch spill round-trip; dur 68->75.6 us. Revert.
// R8: the real R0 finding was VGPR_Count=52 — too small to hold the written
// depth-2 pipeline's >=96 regs of in-flight S/E state. hipcc SANK the
// issue_se(t+1) loads below consume(t), collapsing the pipeline to depth-1
// (load -> full-latency stall -> pack). Fix: __builtin_amdgcn_sched_barrier(0)
// after each issue_se(t+1) pins the prefetch above the consume. Expect VGPR
// ~100-130 (the pipeline state actually materializing) and phase-A stalls to
// shrink from ~latency to ~max(0, latency - consume_time). Keep (256,3):
// VGPR cap 170 leaves headroom, no spill.
// ============================================================================
template <bool USE_WT>
__global__ __launch_bounds__(256, 3)
void mp_kernel(const float* __restrict__ nodes, const int* __restrict__ nlist,
               const float* __restrict__ edges, const unsigned short* __restrict__ wt,
               const float* __restrict__ w, float* __restrict__ out) {
  __shared__ u32 g_lds[16 * 512];   // 32 KB: G (bf16) in phase-B A-frag order

  const int tid = threadIdx.x;
  const int lane = tid & 63;
  const int wid = __builtin_amdgcn_readfirstlane(tid >> 6);
  const int q = lane >> 4, c = lane & 15;

  // XCD-aware mapping: batch b's 4 MB nodes slab pinned to 4 XCDs' L2.
  const int blk = blockIdx.x;
  const int xcd = blk & 7;
  const int batch = xcd >> 2;
  const int ordinal = ((blk >> 3) << 2) + (xcd & 3);    // [0,1024)
  const int wg0 = (batch << LOGN) + (ordinal << 4);
  const float* __restrict__ nbase = nodes + ((size_t)batch << 20);

  const int nd0 = wid << 2;                              // this wave's first node

  auto issue_nl = [&](int t, int4* ni) {
    const int* r = nlist + (((size_t)(wg0 + nd0 + t)) << 5) + (q << 3);
    ni[0] = *(const int4*)r;        // ix[q*8+0 .. +3]
    ni[1] = *(const int4*)(r + 4);  // ix[q*8+4 .. +7]
  };
  auto issue_se = [&](int t, const int4* ni, float* S, float* E) {
    const int ix[8] = {ni[0].x, ni[0].y, ni[0].z, ni[0].w,
                       ni[1].x, ni[1].y, ni[1].z, ni[1].w};
    #pragma unroll
    for (int i = 0; i < 8; ++i) {
      const float* rp = nbase + ((size_t)(u32)ix[i] << 6) + c;
      #pragma unroll
      for (int lt = 0; lt < 4; ++lt) S[i * 4 + lt] = rp[lt << 4];
    }
    const float* ep = edges + (((size_t)(wg0 + nd0 + t)) << 9) + (q << 7) + c;
    #pragma unroll
    for (int i = 0; i < 8; ++i) E[i] = ep[i << 4];
  };
  auto consume = [&](int p, const float* S, const float* E) {
    uint4 apk{pkrne(E[0], E[1]), pkrne(E[2], E[3]),
              pkrne(E[4], E[5]), pkrne(E[6], E[7])};
    const bf16x8 af = __builtin_bit_cast(bf16x8, apk);
    #pragma unroll
    for (int lt = 0; lt < 4; ++lt) {
      uint4 spk{pkrne(S[0 * 4 + lt], S[1 * 4 + lt]),
                pkrne(S[2 * 4 + lt], S[3 * 4 + lt]),
                pkrne(S[4 * 4 + lt], S[5 * 4 + lt]),
                pkrne(S[6 * 4 + lt], S[7 * 4 + lt])};
      f32x4 acc{0.f, 0.f, 0.f, 0.f};
      acc = __builtin_amdgcn_mfma_f32_16x16x32_bf16(af,
              __builtin_bit_cast(bf16x8, spk), acc, 0, 0, 0);
      // lane holds G^T[n=4q+r][L=lt*16+c]; chunk = (2L+(q>>1)) ^ (p&7)
      const u32 lo = pkrne(acc[0], acc[1]);
      const u32 hi = pkrne(acc[2], acc[3]);
      const int chunk = ((((lt << 4) + c) << 1) + (q >> 1)) ^ (p & 7);
      *(uint2*)&g_lds[(p << 9) + (chunk << 2) + ((q & 1) << 1)] = uint2{lo, hi};
    }
  };

  // ---------------- Phase A: pinned depth-2 pipeline ----------------
  // SFENCE() after each issue_se(t+1) forbids the compiler from sinking the
  // prefetch loads below the consume of the other buffer (the R0/R8 finding).
  {
    int4 ni0[2], ni1[2];
    float S0[32], E0[8], S1[32], E1[8];
    issue_nl(0, ni0);
    issue_nl(1, ni1);
    issue_se(0, ni0, S0, E0);       // waits nl(0) only; nl(1) stays in flight
    issue_nl(2, ni0);
    issue_se(1, ni1, S1, E1);       // waits nl(1); SE(0)+nl(2) in flight
    issue_nl(3, ni1);
    SFENCE();                       // SE(0)+SE(1) pinned above consume(0)
    consume(nd0 + 0, S0, E0);       // waits SE(0); SE(1)+nl(3) in flight
    issue_se(2, ni0, S0, E0);
    SFENCE();                       // SE(2) pinned above consume(1)
    consume(nd0 + 1, S1, E1);
    issue_se(3, ni1, S1, E1);
    SFENCE();                       // SE(3) pinned above consume(2)
    consume(nd0 + 2, S0, E0);
    consume(nd0 + 3, S1, E1);
  }

  LGKM0();      // G writes visible
  BARRIER();

  // ---------------- Phase B: out[node][m] = sum_k G2[node][k] * wt[m][k] ----
  // A-frag: lane(q,c): G2[node=c][k=32s+8q+i] -> chunk 4s+q (^c&7), b128.
  const int m = (wid << 4) + c;
  f32x4 ob{0.f, 0.f, 0.f, 0.f};
  if (USE_WT) {
    const unsigned short* wb = wt + ((size_t)m << 10) + (q << 3);
    #pragma unroll 8
    for (int s = 0; s < 32; ++s) {
      uint4 ar = *(const uint4*)&g_lds[(c << 9) + ((((s << 2) + q) ^ (c & 7)) << 2)];
      ob = __builtin_amdgcn_mfma_f32_16x16x32_bf16(__builtin_bit_cast(bf16x8, ar),
                                                   *(const bf16x8*)(wb + (s << 5)),
                                                   ob, 0, 0, 0);
    }
  } else {
    #pragma unroll 4
    for (int s = 0; s < 32; ++s) {
      uint4 ar = *(const uint4*)&g_lds[(c << 9) + ((((s << 2) + q) ^ (c & 7)) << 2)];
      const int l = 2 * s + (q >> 1);
      const float* wp = w + l * 1024 + m * 16 + ((q & 1) << 3);
      ob = __builtin_amdgcn_mfma_f32_16x16x32_bf16(__builtin_bit_cast(bf16x8, ar),
                                                   mk_bw(wp), ob, 0, 0, 0);
    }
  }

  // D: lane(q,c): out[node = 4q+r][mfeat = m]
  #pragma unroll
  for (int r = 0; r < 4; ++r)
    out[((size_t)(wg0 + (q << 2) + r) << 6) + m] = ob[r];
}

extern "C" void kernel_launch(void* const* d_in, const int* in_sizes, int n_in,
                              void* d_out, int out_size, void* d_ws, size_t ws_size,
                              hipStream_t stream) {
  const float* nodes = (const float*)d_in[0];
  const int*   nlist = (const int*)d_in[1];
  const float* edges = (const float*)d_in[2];
  const float* w     = (const float*)d_in[3];
  float* out = (float*)d_out;

  if (ws_size >= 131072) {
    unsigned short* wt = (unsigned short*)d_ws;
    prep_wt<<<256, 256, 0, stream>>>(w, wt);
    mp_kernel<true><<<2048, 256, 0, stream>>>(nodes, nlist, edges, wt, w, out);
  } else {
    mp_kernel<false><<<2048, 256, 0, stream>>>(nodes, nlist, edges, nullptr, w, out);
  }
}